// Round 4
// baseline (131.189 us; speedup 1.0000x reference)
//
#include <hip/hip_runtime.h>

// Problem: TemporalAttention_54322746359850
// Key identity: softmax rows sum to 1, and einsum('TNS,BNH->BNH') sums attn over
// BOTH T and S  =>  y == 1024 * v exactly. The whole adjacency/QK/softmax path is
// dead code. Remaining work:
//   att    = (1024*(h_pred@Wv + bv)) @ Wo + bo
//   gate   = sigmoid( silu([h_pred,h_prev]@gW1 + gb1) @ gW2 + gb2 )
//   h_corr = h_prev + gate*att
//   out    = h_corr + relu([h_corr,h_prev]@mW1 + mb1) @ mW2 + mb2
// Inputs float32 (verified: bf16 reinterpretation gave NaN in R2).
// Output float32 (verified: bf16-packed writes gave ~ref-magnitude error in R3).

#define HH 128
#define NROWS 1024
#define ROWS 4   // rows per block -> grid = 256 blocks = 1 per CU

__global__ __launch_bounds__(HH) void temporal_attn_fused(
    const float* __restrict__ h_prev,
    const float* __restrict__ h_pred,
    const float* __restrict__ Wv, const float* __restrict__ bv,
    const float* __restrict__ Wo, const float* __restrict__ bo,
    const float* __restrict__ gW1, const float* __restrict__ gb1,
    const float* __restrict__ gW2, const float* __restrict__ gb2,
    const float* __restrict__ mW1, const float* __restrict__ mb1,
    const float* __restrict__ mW2, const float* __restrict__ mb2,
    float* __restrict__ out)
{
    __shared__ float sPred[ROWS][HH];
    __shared__ float sPrev[ROWS][HH];
    __shared__ float sBuf[ROWS][HH];    // holds a, then g1, then m1
    __shared__ float sCorr[ROWS][HH];

    const int j = threadIdx.x;
    const int r0 = blockIdx.x * ROWS;

    #pragma unroll
    for (int r = 0; r < ROWS; ++r) {
        sPred[r][j] = h_pred[(r0 + r) * HH + j];
        sPrev[r][j] = h_prev[(r0 + r) * HH + j];
    }
    __syncthreads();

    float acc[ROWS];
    float att[ROWS];

    // ---- step 1: a = 1024*(h_pred @ Wv + bv) -> sBuf ----
    #pragma unroll
    for (int r = 0; r < ROWS; ++r) acc[r] = 0.f;
    #pragma unroll 8
    for (int c = 0; c < HH; ++c) {
        float w = Wv[c * HH + j];
        #pragma unroll
        for (int r = 0; r < ROWS; ++r) acc[r] += sPred[r][c] * w;
    }
    {
        float b = bv[j];
        #pragma unroll
        for (int r = 0; r < ROWS; ++r) sBuf[r][j] = 1024.f * (acc[r] + b);
    }
    __syncthreads();

    // ---- step 2: att = a @ Wo + bo (registers) ----
    #pragma unroll
    for (int r = 0; r < ROWS; ++r) att[r] = 0.f;
    #pragma unroll 8
    for (int c = 0; c < HH; ++c) {
        float w = Wo[c * HH + j];
        #pragma unroll
        for (int r = 0; r < ROWS; ++r) att[r] += sBuf[r][c] * w;
    }
    {
        float b = bo[j];
        #pragma unroll
        for (int r = 0; r < ROWS; ++r) att[r] += b;
    }
    __syncthreads();   // done reading sBuf(a); safe to overwrite below

    // ---- step 3: g1 = silu([h_pred,h_prev] @ gW1 + gb1) -> sBuf ----
    #pragma unroll
    for (int r = 0; r < ROWS; ++r) acc[r] = 0.f;
    #pragma unroll 8
    for (int c = 0; c < HH; ++c) {
        float w = gW1[c * HH + j];
        #pragma unroll
        for (int r = 0; r < ROWS; ++r) acc[r] += sPred[r][c] * w;
    }
    #pragma unroll 8
    for (int c = 0; c < HH; ++c) {
        float w = gW1[(HH + c) * HH + j];
        #pragma unroll
        for (int r = 0; r < ROWS; ++r) acc[r] += sPrev[r][c] * w;
    }
    {
        float b = gb1[j];
        #pragma unroll
        for (int r = 0; r < ROWS; ++r) {
            float x = acc[r] + b;
            sBuf[r][j] = x / (1.f + __expf(-x));   // silu
        }
    }
    __syncthreads();

    // ---- step 4: gate = sigmoid(g1 @ gW2 + gb2); h_corr = h_prev + gate*att -> sCorr ----
    #pragma unroll
    for (int r = 0; r < ROWS; ++r) acc[r] = 0.f;
    #pragma unroll 8
    for (int c = 0; c < HH; ++c) {
        float w = gW2[c * HH + j];
        #pragma unroll
        for (int r = 0; r < ROWS; ++r) acc[r] += sBuf[r][c] * w;
    }
    {
        float b = gb2[j];
        #pragma unroll
        for (int r = 0; r < ROWS; ++r) {
            float g = 1.f / (1.f + __expf(-(acc[r] + b)));
            sCorr[r][j] = sPrev[r][j] + g * att[r];
        }
    }
    __syncthreads();   // sCorr visible; also done reading sBuf(g1)

    // ---- step 5: m1 = relu([h_corr,h_prev] @ mW1 + mb1) -> sBuf ----
    #pragma unroll
    for (int r = 0; r < ROWS; ++r) acc[r] = 0.f;
    #pragma unroll 8
    for (int c = 0; c < HH; ++c) {
        float w = mW1[c * HH + j];
        #pragma unroll
        for (int r = 0; r < ROWS; ++r) acc[r] += sCorr[r][c] * w;
    }
    #pragma unroll 8
    for (int c = 0; c < HH; ++c) {
        float w = mW1[(HH + c) * HH + j];
        #pragma unroll
        for (int r = 0; r < ROWS; ++r) acc[r] += sPrev[r][c] * w;
    }
    {
        float b = mb1[j];
        #pragma unroll
        for (int r = 0; r < ROWS; ++r) sBuf[r][j] = fmaxf(acc[r] + b, 0.f);
    }
    __syncthreads();

    // ---- step 6: out = h_corr + m1 @ mW2 + mb2 ----
    #pragma unroll
    for (int r = 0; r < ROWS; ++r) acc[r] = 0.f;
    #pragma unroll 8
    for (int c = 0; c < HH; ++c) {
        float w = mW2[c * HH + j];
        #pragma unroll
        for (int r = 0; r < ROWS; ++r) acc[r] += sBuf[r][c] * w;
    }
    {
        float b = mb2[j];
        #pragma unroll
        for (int r = 0; r < ROWS; ++r) {
            out[(r0 + r) * HH + j] = sCorr[r][j] + acc[r] + b;
        }
    }
}

extern "C" void kernel_launch(void* const* d_in, const int* in_sizes, int n_in,
                              void* d_out, int out_size, void* d_ws, size_t ws_size,
                              hipStream_t stream) {
    // setup_inputs order:
    // 0 h_prev, 1 h_pred, 2 adj_rows, 3 adj_cols,
    // 4 Wq, 5 bq, 6 Wk, 7 bk, 8 Wv, 9 bv, 10 Wo, 11 bo,
    // 12 gW1, 13 gb1, 14 gW2, 15 gb2, 16 mW1, 17 mb1, 18 mW2, 19 mb2
    const float* h_prev = (const float*)d_in[0];
    const float* h_pred = (const float*)d_in[1];
    const float* Wv  = (const float*)d_in[8];
    const float* bv  = (const float*)d_in[9];
    const float* Wo  = (const float*)d_in[10];
    const float* bo  = (const float*)d_in[11];
    const float* gW1 = (const float*)d_in[12];
    const float* gb1 = (const float*)d_in[13];
    const float* gW2 = (const float*)d_in[14];
    const float* gb2 = (const float*)d_in[15];
    const float* mW1 = (const float*)d_in[16];
    const float* mb1 = (const float*)d_in[17];
    const float* mW2 = (const float*)d_in[18];
    const float* mb2 = (const float*)d_in[19];
    float* out = (float*)d_out;

    dim3 grid(NROWS / ROWS);   // 256 blocks
    dim3 block(HH);            // 128 threads
    hipLaunchKernelGGL(temporal_attn_fused, grid, block, 0, stream,
                       h_prev, h_pred, Wv, bv, Wo, bo,
                       gW1, gb1, gW2, gb2, mW1, mb1, mW2, mb2, out);
}